// Round 13
// baseline (359.317 us; speedup 1.0000x reference)
//
#include <hip/hip_runtime.h>
#include <math.h>

#define N_NODES 50000
#define N_EDGES 400000
#define N_TRAIN 50000
#define IN_DIM  128
#define HIDDEN  512
#define M_PAD   50048   // 391 * 128
#define SCAN_B  196     // 196 * 256 = 50176 >= N_NODES

typedef _Float16 f16;
typedef __attribute__((ext_vector_type(8))) _Float16 f16x8;
typedef __attribute__((ext_vector_type(4))) float f32x4;

// ---------------- graph preprocessing ----------------

__global__ void count_dst_kernel(const int* __restrict__ dst, int* __restrict__ cnt) {
    int i = blockIdx.x * blockDim.x + threadIdx.x;
    if (i < N_EDGES) atomicAdd(&cnt[dst[i]], 1);
}

// per-block sums + dis (fused: saves one launch)
__global__ void scan1_dis_kernel(const int* __restrict__ cnt, int* __restrict__ bsum,
                                 float* __restrict__ dis) {
    __shared__ int red[256];
    int t = threadIdx.x, i = blockIdx.x * 256 + t;
    int v = (i < N_NODES) ? cnt[i] : 0;
    if (i < N_NODES) dis[i] = rsqrtf(1.0f + (float)v);  // +1 self-loop
    red[t] = v;
    __syncthreads();
    for (int o = 128; o > 0; o >>= 1) {
        if (t < o) red[t] += red[t + o];
        __syncthreads();
    }
    if (t == 0) bsum[blockIdx.x] = red[0];
}

// local scan + inline scan of the 196 block sums (replaces scan2+scan3)
__global__ void scan3_kernel(const int* __restrict__ cnt, const int* __restrict__ bsum,
                             int* __restrict__ off) {
    __shared__ int bpart[256];
    __shared__ int part[256];
    int t = threadIdx.x;
    int bv = (t < SCAN_B) ? bsum[t] : 0;
    bpart[t] = bv;
    __syncthreads();
    for (int o = 1; o < 256; o <<= 1) {
        int u = (t >= o) ? bpart[t - o] : 0;
        __syncthreads();
        bpart[t] += u;
        __syncthreads();
    }
    int base = (blockIdx.x > 0) ? bpart[blockIdx.x - 1] : 0;   // exclusive block prefix
    int i = blockIdx.x * 256 + t;
    int v = (i < N_NODES) ? cnt[i] : 0;
    part[t] = v;
    __syncthreads();
    for (int o = 1; o < 256; o <<= 1) {
        int u = (t >= o) ? part[t - o] : 0;
        __syncthreads();
        part[t] += u;
        __syncthreads();
    }
    int excl = part[t] - v;
    if (i < N_NODES) off[i] = base + excl;
    if (i == N_NODES - 1) off[N_NODES] = base + excl + v;   // total
}

// CSR fill; precompute per-edge src-side norm weight.
__global__ void fill_csr_kernel(const int* __restrict__ src, const int* __restrict__ dst,
                                const int* __restrict__ off, int* __restrict__ cursor,
                                const float* __restrict__ dis,
                                int* __restrict__ csr_src, float* __restrict__ csr_w) {
    int i = blockIdx.x * blockDim.x + threadIdx.x;
    if (i < N_EDGES) {
        int d = dst[i], s = src[i];
        int p = atomicAdd(&cursor[d], 1);
        int idx = off[d] + p;
        csr_src[idx] = s;
        csr_w[idx] = dis[s];
    }
}

// ---- all three weight conversions in one launch: W[K][512] -> Bt[512][K] f16 ----
__global__ void convw_all_kernel(const float* __restrict__ W1, const float* __restrict__ W2,
                                 const float* __restrict__ W3, f16* __restrict__ Bt1,
                                 f16* __restrict__ Bt2, f16* __restrict__ Bt3) {
    const int S1 = IN_DIM * HIDDEN;          // 65536
    const int S2 = S1 + HIDDEN * HIDDEN;     // 327680
    const int S3 = S2 + HIDDEN * HIDDEN;     // 589824
    int idx = blockIdx.x * blockDim.x + threadIdx.x;
    if (idx >= S3) return;
    if (idx < S1) {
        int k = idx / HIDDEN, n = idx % HIDDEN;
        Bt1[(size_t)n * IN_DIM + k] = (f16)W1[idx];
    } else if (idx < S2) {
        int j = idx - S1;
        int k = j / HIDDEN, n = j % HIDDEN;
        Bt2[(size_t)n * HIDDEN + k] = (f16)W2[j];
    } else {
        int j = idx - S2;
        int k = j / HIDDEN, n = j % HIDDEN;
        Bt3[(size_t)n * HIDDEN + k] = (f16)W3[j];
    }
}

// ---- x -> f16 (halves agg<128>'s gather traffic) ----
__global__ void xcast_kernel(const float* __restrict__ x, f16* __restrict__ XF) {
    int i = blockIdx.x * blockDim.x + threadIdx.x;   // one f16x8 per thread
    if (i >= N_NODES * IN_DIM / 8) return;
    const float4* p = (const float4*)x + (size_t)i * 2;
    float4 a = p[0], b = p[1];
    f16x8 o = {(f16)a.x, (f16)a.y, (f16)a.z, (f16)a.w,
               (f16)b.x, (f16)b.y, (f16)b.z, (f16)b.w};
    __builtin_nontemporal_store(o, (f16x8*)XF + i);
}

// ------- aggregation: fp16 h (D wide) -> fp16, cascaded 8/4/2/1 unroll, nt output -------
template <int D>
__global__ void agg_kernel(const f16* __restrict__ h, const float* __restrict__ dis,
                           const int* __restrict__ off, const int* __restrict__ csr_src,
                           const float* __restrict__ csr_w, f16* __restrict__ A) {
    const int TPN = D / 8;
    const int NPB = 256 / TPN;
    int node = blockIdx.x * NPB + threadIdx.x / TPN;
    if (node >= N_NODES) return;
    int t = threadIdx.x % TPN;
    float dv = dis[node];
    float w0 = dv * dv;
    f16x8 a = *(const f16x8*)&h[(size_t)node * D + t * 8];
    float acc0[8], acc1[8];
    #pragma unroll
    for (int j = 0; j < 8; j++) { acc0[j] = w0 * (float)a[j]; acc1[j] = 0.f; }
    int s0 = off[node], s1 = off[node + 1];
    int k = s0;
    for (; k + 8 <= s1; k += 8) {
        f16x8 b[8];
        float w[8];
        #pragma unroll
        for (int u = 0; u < 8; u++) {
            int su = csr_src[k + u];
            w[u] = csr_w[k + u] * dv;
            b[u] = *(const f16x8*)&h[(size_t)su * D + t * 8];
        }
        #pragma unroll
        for (int j = 0; j < 8; j++) {
            acc0[j] = fmaf(w[0], (float)b[0][j], acc0[j]);
            acc1[j] = fmaf(w[1], (float)b[1][j], acc1[j]);
            acc0[j] = fmaf(w[2], (float)b[2][j], acc0[j]);
            acc1[j] = fmaf(w[3], (float)b[3][j], acc1[j]);
            acc0[j] = fmaf(w[4], (float)b[4][j], acc0[j]);
            acc1[j] = fmaf(w[5], (float)b[5][j], acc1[j]);
            acc0[j] = fmaf(w[6], (float)b[6][j], acc0[j]);
            acc1[j] = fmaf(w[7], (float)b[7][j], acc1[j]);
        }
    }
    if (k + 4 <= s1) {
        f16x8 b[4];
        float w[4];
        #pragma unroll
        for (int u = 0; u < 4; u++) {
            int su = csr_src[k + u];
            w[u] = csr_w[k + u] * dv;
            b[u] = *(const f16x8*)&h[(size_t)su * D + t * 8];
        }
        #pragma unroll
        for (int j = 0; j < 8; j++) {
            acc0[j] = fmaf(w[0], (float)b[0][j], acc0[j]);
            acc1[j] = fmaf(w[1], (float)b[1][j], acc1[j]);
            acc0[j] = fmaf(w[2], (float)b[2][j], acc0[j]);
            acc1[j] = fmaf(w[3], (float)b[3][j], acc1[j]);
        }
        k += 4;
    }
    if (k + 2 <= s1) {
        int sa = csr_src[k], sb = csr_src[k + 1];
        float wa = csr_w[k] * dv, wb = csr_w[k + 1] * dv;
        f16x8 ba = *(const f16x8*)&h[(size_t)sa * D + t * 8];
        f16x8 bb = *(const f16x8*)&h[(size_t)sb * D + t * 8];
        #pragma unroll
        for (int j = 0; j < 8; j++) {
            acc0[j] = fmaf(wa, (float)ba[j], acc0[j]);
            acc1[j] = fmaf(wb, (float)bb[j], acc1[j]);
        }
        k += 2;
    }
    if (k < s1) {
        int sa = csr_src[k];
        float wa = csr_w[k] * dv;
        f16x8 ba = *(const f16x8*)&h[(size_t)sa * D + t * 8];
        #pragma unroll
        for (int j = 0; j < 8; j++) acc0[j] = fmaf(wa, (float)ba[j], acc0[j]);
    }
    f16x8 o;
    #pragma unroll
    for (int j = 0; j < 8; j++) o[j] = (f16)(acc0[j] + acc1[j]);
    __builtin_nontemporal_store(o, (f16x8*)&A[(size_t)node * D + t * 8]);
}

// ------- MFMA fp16 GEMM: 128x128 tile, 4 waves, single-buffer, 4 blocks/CU -------
// C[M][512] = tanh(A @ B + bias).  BK=64; 32 MFMA/wave/step.
// XOR-swizzle per rule #21 (linear LDS dest + inverse-swizzled global src + swizzled read).
// Epilogue: acc -> LDS (stride 136 f16, 16B-aligned slots) -> coalesced nt f16x8 stores.
__global__ __launch_bounds__(256, 4) void gemm_mfma_kernel(
    const f16* __restrict__ A, const f16* __restrict__ Bt, const float* __restrict__ bias,
    f16* __restrict__ C, int M, int Kb) {
    __shared__ f16 smem[17408];          // K-loop: As[8192]|Bs[8192]=32KB; epilogue: 128x136
    f16* As = smem;
    f16* Bs = smem + 8192;
    int tid = threadIdx.x;
    int lane = tid & 63, wv = tid >> 6;
    int wr = wv >> 1, wc = wv & 1;       // 2x2 waves, 64x64 output each

    // bijective XCD swizzle (m204); grid 1564 = 4 * 391
    int nwg = gridDim.x;
    int q = nwg >> 3, r = nwg & 7;
    int xcd = blockIdx.x & 7, pos = blockIdx.x >> 3;
    int wgid = (xcd < r ? xcd * (q + 1) : r * (q + 1) + (xcd - r) * q) + pos;
    int j0 = (wgid & 3) * 128;           // 4 col tiles
    int i0 = (wgid >> 2) * 128;          // 391 row tiles

    int l15 = lane & 15, l4 = lane >> 4;

    f32x4 acc[4][4];
    #pragma unroll
    for (int m = 0; m < 4; m++)
        #pragma unroll
        for (int n = 0; n < 4; n++)
            acc[m][n] = (f32x4){0.f, 0.f, 0.f, 0.f};

    const int nt = Kb / 64;
    for (int t = 0; t < nt; t++) {
        int k0 = t * 64;
        if (t) __syncthreads();          // previous step's readers done -> LDS reusable
        #pragma unroll
        for (int i = 0; i < 4; i++) {    // A: 128x64 = 1024 slots (4 loads/thread)
            int s = i * 256 + tid;
            int row = s >> 3, c8 = s & 7;
            int c8s = c8 ^ (row & 7);    // inverse-swizzled source column
            const f16* gp = A + (size_t)(i0 + row) * Kb + k0 + c8s * 8;
            f16* lp = &As[(i * 256 + wv * 64) * 8];   // wave-uniform base
            __builtin_amdgcn_global_load_lds(
                (const __attribute__((address_space(1))) void*)gp,
                (__attribute__((address_space(3))) void*)lp, 16, 0, 0);
        }
        #pragma unroll
        for (int i = 0; i < 4; i++) {    // B: 128x64 = 1024 slots (4 loads/thread)
            int s = i * 256 + tid;
            int row = s >> 3, c8 = s & 7;
            int c8s = c8 ^ (row & 7);
            const f16* gp = Bt + (size_t)(j0 + row) * Kb + k0 + c8s * 8;
            f16* lp = &Bs[(i * 256 + wv * 64) * 8];
            __builtin_amdgcn_global_load_lds(
                (const __attribute__((address_space(1))) void*)gp,
                (__attribute__((address_space(3))) void*)lp, 16, 0, 0);
        }
        __syncthreads();                 // drain vmcnt -> tiles resident

        f16x8 af[4][2], bfr[4][2];
        #pragma unroll
        for (int m = 0; m < 4; m++) {
            int row = wr * 64 + m * 16 + l15;
            #pragma unroll
            for (int kk = 0; kk < 2; kk++) {
                int slot = (kk * 4 + l4) ^ (row & 7);
                af[m][kk] = *(const f16x8*)&As[row * 64 + slot * 8];
            }
        }
        #pragma unroll
        for (int n = 0; n < 4; n++) {
            int brow = wc * 64 + n * 16 + l15;
            #pragma unroll
            for (int kk = 0; kk < 2; kk++) {
                int slot = (kk * 4 + l4) ^ (brow & 7);
                bfr[n][kk] = *(const f16x8*)&Bs[brow * 64 + slot * 8];
            }
        }
        #pragma unroll
        for (int m = 0; m < 4; m++)
            #pragma unroll
            for (int n = 0; n < 4; n++)
                #pragma unroll
                for (int kk = 0; kk < 2; kk++)
                    acc[m][n] = __builtin_amdgcn_mfma_f32_16x16x32_f16(
                        af[m][kk], bfr[n][kk], acc[m][n], 0, 0, 0);
    }

    // ---- epilogue: acc -> LDS (stride 136 = 16B-aligned slots) -> coalesced nt stores ----
    __syncthreads();                     // all waves done reading K-loop LDS
    #pragma unroll
    for (int m = 0; m < 4; m++) {
        #pragma unroll
        for (int n = 0; n < 4; n++) {
            int lcol = wc * 64 + n * 16 + l15;
            float bc = bias[j0 + lcol];
            #pragma unroll
            for (int rr = 0; rr < 4; rr++) {
                int lrow = wr * 64 + m * 16 + l4 * 4 + rr;
                smem[lrow * 136 + lcol] = (f16)tanhf(acc[m][n][rr] + bc);
            }
        }
    }
    __syncthreads();
    #pragma unroll
    for (int j = 0; j < 8; j++) {        // 128 rows x 16 chunks of 16B
        int qq = j * 256 + tid;
        int row = qq >> 4, c8 = qq & 15;
        int grow = i0 + row;
        if (grow < M) {
            f16x8 v = *(const f16x8*)&smem[row * 136 + c8 * 8];
            __builtin_nontemporal_store(v, (f16x8*)&C[(size_t)grow * HIDDEN + j0 + c8 * 8]);
        }
    }
}

// ---------------- final edge scoring (fp16 input) ----------------
__global__ void edge_score_kernel(const f16* __restrict__ h,
                                  const int* __restrict__ src, const int* __restrict__ dst,
                                  const int* __restrict__ te, const float* __restrict__ wgt,
                                  const float* __restrict__ fc2b, float* __restrict__ out) {
    int wid = threadIdx.x / 64;
    int lane = threadIdx.x % 64;
    int e = blockIdx.x * 4 + wid;
    if (e >= N_TRAIN) return;
    int id = te[e];
    int a = src[id], b = dst[id];
    f16x8 ha = *(const f16x8*)&h[(size_t)a * HIDDEN + lane * 8];
    f16x8 hb = *(const f16x8*)&h[(size_t)b * HIDDEN + lane * 8];
    float4 w0 = *(const float4*)&wgt[lane * 8];
    float4 w1 = *(const float4*)&wgt[lane * 8 + 4];
    float acc = 0.f;
    acc += (float)ha[0] * (float)hb[0] * w0.x;
    acc += (float)ha[1] * (float)hb[1] * w0.y;
    acc += (float)ha[2] * (float)hb[2] * w0.z;
    acc += (float)ha[3] * (float)hb[3] * w0.w;
    acc += (float)ha[4] * (float)hb[4] * w1.x;
    acc += (float)ha[5] * (float)hb[5] * w1.y;
    acc += (float)ha[6] * (float)hb[6] * w1.z;
    acc += (float)ha[7] * (float)hb[7] * w1.w;
    #pragma unroll
    for (int o = 32; o > 0; o >>= 1) acc += __shfl_down(acc, o);
    if (lane == 0) out[e] = acc + fc2b[0];
}

// ---------------- launch ----------------

extern "C" void kernel_launch(void* const* d_in, const int* in_sizes, int n_in,
                              void* d_out, int out_size, void* d_ws, size_t ws_size,
                              hipStream_t stream) {
    const float* x    = (const float*)d_in[0];
    const int*   eidx = (const int*)d_in[1];
    const int*   te   = (const int*)d_in[2];
    const float* W1   = (const float*)d_in[3];
    const float* b1   = (const float*)d_in[4];
    const float* W2   = (const float*)d_in[5];
    const float* b2   = (const float*)d_in[6];
    const float* W3   = (const float*)d_in[7];
    const float* b3   = (const float*)d_in[8];
    const float* fc2W = (const float*)d_in[9];
    const float* fc2b = (const float*)d_in[10];
    const int* srcp = eidx;
    const int* dstp = eidx + N_EDGES;

    char* ws = (char*)d_ws;
    size_t used = 0;
    auto alloc = [&](size_t bytes) {
        void* p = ws + used;
        used += (bytes + 255) / 256 * 256;
        return p;
    };
    int*   cnt     = (int*)alloc((size_t)N_NODES * 4);
    int*   off     = (int*)alloc((size_t)(N_NODES + 1) * 4);
    int*   cursor  = (int*)alloc((size_t)N_NODES * 4);
    int*   bsum    = (int*)alloc((size_t)SCAN_B * 4);
    int*   csr_src = (int*)alloc((size_t)N_EDGES * 4);
    float* csr_w   = (float*)alloc((size_t)N_EDGES * 4);
    float* dis     = (float*)alloc((size_t)N_NODES * 4);
    f16* Bt1 = (f16*)alloc((size_t)HIDDEN * IN_DIM * 2);
    f16* Bt2 = (f16*)alloc((size_t)HIDDEN * HIDDEN * 2);
    f16* Bt3 = (f16*)alloc((size_t)HIDDEN * HIDDEN * 2);
    f16* XF  = (f16*)alloc((size_t)N_NODES * IN_DIM * 2);  // f16 copy of x
    f16* GA  = (f16*)alloc((size_t)M_PAD * HIDDEN * 2);    // GEMM A operand
    f16* F   = (f16*)alloc((size_t)M_PAD * HIDDEN * 2);    // layer output

    if (used > ws_size) return;  // fail cleanly rather than OOB

    hipMemsetAsync(cnt, 0, (size_t)N_NODES * 4, stream);
    hipMemsetAsync(cursor, 0, (size_t)N_NODES * 4, stream);

    count_dst_kernel<<<(N_EDGES + 255) / 256, 256, 0, stream>>>(dstp, cnt);
    scan1_dis_kernel<<<SCAN_B, 256, 0, stream>>>(cnt, bsum, dis);
    scan3_kernel<<<SCAN_B, 256, 0, stream>>>(cnt, bsum, off);
    fill_csr_kernel<<<(N_EDGES + 255) / 256, 256, 0, stream>>>(srcp, dstp, off, cursor, dis,
                                                               csr_src, csr_w);
    convw_all_kernel<<<(589824 + 255) / 256, 256, 0, stream>>>(W1, W2, W3, Bt1, Bt2, Bt3);
    xcast_kernel<<<(N_NODES * IN_DIM / 8 + 255) / 256, 256, 0, stream>>>(x, XF);

    int gemm_blocks = (HIDDEN / 128) * (M_PAD / 128);   // 1564, 1D for XCD swizzle

    // layer 1: GA = agg(XF);  F = tanh(GA @ W1 + b1)
    agg_kernel<IN_DIM><<<(N_NODES + 15) / 16, 256, 0, stream>>>(XF, dis, off, csr_src,
                                                                csr_w, GA);
    gemm_mfma_kernel<<<gemm_blocks, 256, 0, stream>>>(GA, Bt1, b1, F, N_NODES, IN_DIM);
    // layer 2
    agg_kernel<HIDDEN><<<(N_NODES + 3) / 4, 256, 0, stream>>>(F, dis, off, csr_src,
                                                              csr_w, GA);
    gemm_mfma_kernel<<<gemm_blocks, 256, 0, stream>>>(GA, Bt2, b2, F, N_NODES, HIDDEN);
    // layer 3
    agg_kernel<HIDDEN><<<(N_NODES + 3) / 4, 256, 0, stream>>>(F, dis, off, csr_src,
                                                              csr_w, GA);
    gemm_mfma_kernel<<<gemm_blocks, 256, 0, stream>>>(GA, Bt3, b3, F, N_NODES, HIDDEN);
    // final scoring
    edge_score_kernel<<<(N_TRAIN + 3) / 4, 256, 0, stream>>>(F, srcp, dstp, te, fc2W, fc2b,
                                                             (float*)d_out);
}